// Round 1
// baseline (1848.392 us; speedup 1.0000x reference)
//
#include <hip/hip_runtime.h>
#include <cfloat>
#include <cmath>

// Problem constants (from reference)
#define NN 16384
#define H 4
#define D 64
#define B 512
#define KNBR 8          // neighbors kept
#define KSEL 9          // K+1 selected (closest is self, dropped)
#define NC 32           // node chunks for partial KNN
#define CS (NN / NC)    // 512 nodes per chunk
#define NQ (2 * B)      // 1024 queries (src then dst)

// ---------------------------------------------------------------- kernel 1
// pn2[n*H+h] = sum_d pos[n,h,d]^2
__global__ __launch_bounds__(256) void pn2_kernel(const float* __restrict__ pos,
                                                  float* __restrict__ pn2) {
    int i = blockIdx.x * blockDim.x + threadIdx.x;   // 0 .. N*H
    if (i >= NN * H) return;
    const float4* p = (const float4*)(pos + (size_t)i * D);
    float s = 0.f;
#pragma unroll
    for (int d = 0; d < D / 4; ++d) {
        float4 v = p[d];
        s += v.x * v.x + v.y * v.y + v.z * v.z + v.w * v.w;
    }
    pn2[i] = s;
}

// ---------------------------------------------------------------- kernel 2
// Partial KNN: lane = query, block-uniform node loop (scalar loads broadcast).
// grid = (NQ/64, H, NC), block = 64
__global__ __launch_bounds__(64) void knn_partial(const float* __restrict__ pos,
                                                  const float* __restrict__ pn2,
                                                  const int* __restrict__ edges,
                                                  float* __restrict__ part_d,
                                                  int* __restrict__ part_i) {
    const int lane = threadIdx.x;
    const int q = blockIdx.x * 64 + lane;     // 0..1023; query node = edges[q]
    const int h = blockIdx.y;
    const int c = blockIdx.z;

    const int node = edges[q];
    const float* qp = pos + ((size_t)node * H + h) * D;
    float qv[D];
#pragma unroll
    for (int d = 0; d < D; ++d) qv[d] = qp[d];
    float q2 = 0.f;
#pragma unroll
    for (int d = 0; d < D; ++d) q2 = fmaf(qv[d], qv[d], q2);

    float bd[KSEL];
    int   bi[KSEL];
#pragma unroll
    for (int j = 0; j < KSEL; ++j) { bd[j] = FLT_MAX; bi[j] = -1; }

    const int n0 = c * CS;
    for (int n = n0; n < n0 + CS; ++n) {
        const float* p = pos + ((size_t)n * H + h) * D;   // block-uniform -> s_load
        float a0 = 0.f, a1 = 0.f, a2 = 0.f, a3 = 0.f;
#pragma unroll
        for (int d = 0; d < D; d += 4) {
            a0 = fmaf(p[d + 0], qv[d + 0], a0);
            a1 = fmaf(p[d + 1], qv[d + 1], a1);
            a2 = fmaf(p[d + 2], qv[d + 2], a2);
            a3 = fmaf(p[d + 3], qv[d + 3], a3);
        }
        float cross = (a0 + a1) + (a2 + a3);
        float d2 = fmaf(-2.f, cross, pn2[n * H + h] + q2);
        if (d2 < bd[KSEL - 1]) {          // rare divergent insert
            float dc = d2; int ic = n;
#pragma unroll
            for (int j = 0; j < KSEL; ++j) {
                if (dc < bd[j]) {
                    float td = bd[j]; int ti = bi[j];
                    bd[j] = dc; bi[j] = ic;
                    dc = td; ic = ti;
                }
            }
        }
    }
    size_t base = ((size_t)(q * H + h) * NC + c) * KSEL;
#pragma unroll
    for (int j = 0; j < KSEL; ++j) { part_d[base + j] = bd[j]; part_i[base + j] = bi[j]; }
}

// ---------------------------------------------------------------- kernel 3
// Merge NC sorted 9-lists per (q,h) -> pop 9 global minima, drop first (self).
// grid = NQ*H, block = 64 (lanes >= NC idle with +inf)
__global__ __launch_bounds__(64) void knn_merge(const float* __restrict__ part_d,
                                                const int* __restrict__ part_i,
                                                float* __restrict__ knn_d,
                                                int* __restrict__ knn_i) {
    const int lane = threadIdx.x;
    const int qh = blockIdx.x;
    float d[KSEL]; int idx[KSEL];
    if (lane < NC) {
        size_t base = ((size_t)qh * NC + lane) * KSEL;
#pragma unroll
        for (int j = 0; j < KSEL; ++j) { d[j] = part_d[base + j]; idx[j] = part_i[base + j]; }
    } else {
#pragma unroll
        for (int j = 0; j < KSEL; ++j) { d[j] = FLT_MAX; idx[j] = -1; }
    }
    for (int s = 0; s < KSEL; ++s) {
        float v = d[0]; int who = lane;
#pragma unroll
        for (int off = 1; off < 64; off <<= 1) {
            float v2 = __shfl_xor(v, off);
            int   w2 = __shfl_xor(who, off);
            if (v2 < v || (v2 == v && w2 < who)) { v = v2; who = w2; }  // total order -> converges
        }
        int wi = __shfl(idx[0], who);
        if (s > 0 && lane == 0) {
            knn_d[(size_t)qh * KNBR + (s - 1)] = sqrtf(fmaxf(v, 0.f));
            knn_i[(size_t)qh * KNBR + (s - 1)] = wi;
        }
        if (lane == who) {
#pragma unroll
            for (int j = 0; j < KSEL - 1; ++j) { d[j] = d[j + 1]; idx[j] = idx[j + 1]; }
            d[KSEL - 1] = FLT_MAX; idx[KSEL - 1] = -1;
        }
    }
}

// ---------------------------------------------------------------- kernel 4
// Per-edge logits + softmax(+8 sentinels dist=1, logit=0) + sigmoid(mean_h).
// grid = B, block = 64: lane = h*16 + t, t<8: src side, t>=8: dst side
__global__ __launch_bounds__(64) void finalize(const float* __restrict__ pos,
                                               const float* __restrict__ grads,
                                               const float* __restrict__ adj,
                                               const float* __restrict__ label_w,
                                               const int* __restrict__ edges,
                                               const float* __restrict__ knn_d,
                                               const int* __restrict__ knn_i,
                                               float* __restrict__ out) {
    const int b = blockIdx.x;
    const int lane = threadIdx.x;
    const int h = lane >> 4;
    const int t = lane & 15;
    const int sb = edges[b];
    const int db = edges[B + b];
    const float lw = label_w[0];

    int q, qn, gn;
    if (t < KNBR) { q = b;     qn = sb; gn = db; }   // src side: grads at dst
    else          { q = B + b; qn = db; gn = sb; }   // dst side: grads at src
    const int k = t & 7;
    const size_t kk = ((size_t)q * H + h) * KNBR + k;
    const int j = knn_i[kk];
    const float dist = knn_d[kk];
    const size_t adj_idx = (t < KNBR) ? ((size_t)j * NN + db) : ((size_t)sb * NN + j);

    const float* pq = pos + ((size_t)qn * H + h) * D;
    const float* pj = pos + ((size_t)j * H + h) * D;
    const float* g = grads + ((size_t)gn * H + h) * D;
    float contrib = 0.f;
#pragma unroll
    for (int d = 0; d < D; ++d) contrib = fmaf(pq[d] - pj[d], g[d], contrib);
    float logit = fmaf(lw, adj[adj_idx], contrib);

    // softmax over 24 entries (16 real + 8 sentinels at dist 1.0, logit 0)
    float dmin = dist;
#pragma unroll
    for (int off = 1; off < 16; off <<= 1) dmin = fminf(dmin, __shfl_xor(dmin, off));
    dmin = fminf(dmin, 1.0f);             // include sentinels in the max(-d)
    float e = expf(dmin - dist);
    float num = e * logit;
    float den = e;
#pragma unroll
    for (int off = 1; off < 16; off <<= 1) {
        num += __shfl_xor(num, off);
        den += __shfl_xor(den, off);
    }
    den += 8.f * expf(dmin - 1.0f);
    float val = num / den;                // identical on all 16 lanes of this head

    // sum over 64 lanes = 16 * sum_h val ; mean over H=4 -> /64
#pragma unroll
    for (int off = 1; off < 64; off <<= 1) val += __shfl_xor(val, off);
    if (lane == 0) {
        float m = val * (1.f / 64.f);
        out[b] = 1.f / (1.f + expf(-m));
    }
}

// ----------------------------------------------------------------
extern "C" void kernel_launch(void* const* d_in, const int* in_sizes, int n_in,
                              void* d_out, int out_size, void* d_ws, size_t ws_size,
                              hipStream_t stream) {
    const float* pos     = (const float*)d_in[0];
    const float* grads   = (const float*)d_in[1];
    const float* adj     = (const float*)d_in[2];
    const float* label_w = (const float*)d_in[3];
    const int*   edges   = (const int*)d_in[4];
    float* out = (float*)d_out;

    // workspace layout
    float* pn2    = (float*)d_ws;                       // N*H
    float* part_d = pn2 + (size_t)NN * H;               // NQ*H*NC*KSEL
    int*   part_i = (int*)(part_d + (size_t)NQ * H * NC * KSEL);
    float* knn_dd = (float*)(part_i + (size_t)NQ * H * NC * KSEL);  // NQ*H*KNBR
    int*   knn_ii = (int*)(knn_dd + (size_t)NQ * H * KNBR);

    pn2_kernel<<<(NN * H + 255) / 256, 256, 0, stream>>>(pos, pn2);
    knn_partial<<<dim3(NQ / 64, H, NC), 64, 0, stream>>>(pos, pn2, edges, part_d, part_i);
    knn_merge<<<NQ * H, 64, 0, stream>>>(part_d, part_i, knn_dd, knn_ii);
    finalize<<<B, 64, 0, stream>>>(pos, grads, adj, label_w, edges, knn_dd, knn_ii, out);
}

// Round 2
// 1456.424 us; speedup vs baseline: 1.2691x; 1.2691x over previous
//
#include <hip/hip_runtime.h>
#include <hip/hip_bf16.h>
#include <cfloat>
#include <cmath>

// Problem constants
#define NN 16384
#define H 4
#define D 64
#define B 512
#define KNBR 8          // neighbors kept per side
#define NC 64           // node chunks (256 nodes each)
#define NQ (2 * B)      // 1024 queries (src then dst)

typedef __attribute__((ext_vector_type(8))) short bf16x8;   // 8 bf16 = 4 VGPRs
typedef __attribute__((ext_vector_type(4))) float f32x4;

static __device__ __forceinline__ ushort f2bf(float v) {
    __hip_bfloat16 b = __float2bfloat16(v);
    return *(ushort*)&b;
}

// ---------------------------------------------------------------- kernel 1
// pn2h[h*N+n] = |pos[n,h,:]|^2 (exact fp32); posb[h][n][d] = bf16(pos[n,h,d])
__global__ __launch_bounds__(256) void prep_pos(const float* __restrict__ pos,
                                                ushort* __restrict__ posb,
                                                float* __restrict__ pn2h) {
    int i = blockIdx.x * 256 + threadIdx.x;       // i = h*NN + n
    if (i >= NN * H) return;
    int h = i / NN, n = i % NN;
    const float* src = pos + ((size_t)n * H + h) * D;
    ushort* dst = posb + (size_t)i * D;
    float s = 0.f;
#pragma unroll
    for (int d = 0; d < D; d += 4) {
        float4 v = *(const float4*)(src + d);
        s += v.x * v.x + v.y * v.y + v.z * v.z + v.w * v.w;
        ushort4 u; u.x = f2bf(v.x); u.y = f2bf(v.y); u.z = f2bf(v.z); u.w = f2bf(v.w);
        *(ushort4*)(dst + d) = u;
    }
    pn2h[i] = s;
}

// ---------------------------------------------------------------- kernel 2
// qb[h][q][d] = posb[h][edges[q]][d]
__global__ __launch_bounds__(256) void prep_q(const ushort* __restrict__ posb,
                                              const int* __restrict__ edges,
                                              ushort* __restrict__ qb) {
    int tid = blockIdx.x * 256 + threadIdx.x;     // h*NQ*64 + q*64 + d
    if (tid >= H * NQ * D) return;
    int d = tid & 63;
    int q = (tid >> 6) & (NQ - 1);
    int h = tid >> 16;                            // /(NQ*64)
    int node = edges[q];
    qb[tid] = posb[((size_t)h * NN + node) * D + d];
}

// ---------------------------------------------------------------- kernel 3
// MFMA distance tiles + fused per-chunk top-8.
// grid = (NQ/16, H, NC), block = 64 (one wave).
// Wave computes cross for 16 queries x 256 nodes via 16 col-tiles of
// mfma_f32_16x16x32_bf16 (K=64 -> 2 mfma/tile). Epilogue: rank by
// key = pn2[n] - 2*cross (qn2 added at merge), self excluded by index,
// per-lane insertion top-8 then 16-lane butterfly pop-merge per query row.
__global__ __launch_bounds__(64, 3) void knn_mfma(const ushort* __restrict__ posb,
                                                  const float* __restrict__ pn2h,
                                                  const ushort* __restrict__ qb,
                                                  const int* __restrict__ edges,
                                                  float* __restrict__ part_d,
                                                  int* __restrict__ part_i) {
    const int lane = threadIdx.x;
    const int qt = blockIdx.x;        // query tile (16 queries)
    const int h  = blockIdx.y;
    const int c  = blockIdx.z;        // node chunk (256 nodes)
    const int col  = lane & 15;
    const int quad = lane >> 4;
    const int n0 = c * 256;

    // A fragments: row q = qt*16+col, k = quad*8 + {0..7} (+32 for a1)
    const ushort* qrow = qb + ((size_t)h * NQ + qt * 16 + col) * D + quad * 8;
    bf16x8 a0 = *(const bf16x8*)qrow;
    bf16x8 a1 = *(const bf16x8*)(qrow + 32);

    const ushort* prow = posb + ((size_t)h * NN + n0 + col) * D + quad * 8;

    f32x4 acc[16];
#pragma unroll
    for (int t = 0; t < 16; ++t) {
        bf16x8 b0 = *(const bf16x8*)(prow + (size_t)t * 16 * D);
        bf16x8 b1 = *(const bf16x8*)(prow + (size_t)t * 16 * D + 32);
        f32x4 z = {0.f, 0.f, 0.f, 0.f};
        z = __builtin_amdgcn_mfma_f32_16x16x32_bf16(a0, b0, z, 0, 0, 0);
        acc[t] = __builtin_amdgcn_mfma_f32_16x16x32_bf16(a1, b1, z, 0, 0, 0);
    }

    // pn2 for my 16 columns (one per tile)
    float p2[16];
#pragma unroll
    for (int t = 0; t < 16; ++t) p2[t] = pn2h[(size_t)h * NN + n0 + t * 16 + col];

    // query node ids for my 4 rows (rows m = quad*4 + r)
    int qn[4];
#pragma unroll
    for (int r = 0; r < 4; ++r) qn[r] = edges[qt * 16 + quad * 4 + r];

    // selection: serial over r (C/D layout: value(row=quad*4+r, col) = acc[t][r])
    for (int r = 0; r < 4; ++r) {
        float bd[KNBR]; int bt[KNBR];
#pragma unroll
        for (int j = 0; j < KNBR; ++j) { bd[j] = FLT_MAX; bt[j] = 0; }
#pragma unroll
        for (int t = 0; t < 16; ++t) {
            float key = fmaf(-2.f, acc[t][r], p2[t]);
            int n = n0 + t * 16 + col;
            if (n == qn[r]) key = FLT_MAX;        // exclude self
            if (key < bd[KNBR - 1]) {
                float dc = key; int tc = t;
#pragma unroll
                for (int j = 0; j < KNBR; ++j) {
                    if (dc < bd[j]) {
                        float td = bd[j]; int ti = bt[j];
                        bd[j] = dc; bt[j] = tc; dc = td; tc = ti;
                    }
                }
            }
        }
        // 16-lane pop-merge (4 query rows in parallel across the wave)
        const int pq = qt * 16 + quad * 4 + r;
        const size_t obase = (((size_t)pq * H + h) * NC + c) * KNBR;
        for (int s = 0; s < KNBR; ++s) {
            float v = bd[0]; int who = lane;
#pragma unroll
            for (int off = 1; off < 16; off <<= 1) {
                float v2 = __shfl_xor(v, off);
                int   w2 = __shfl_xor(who, off);
                if (v2 < v || (v2 == v && w2 < who)) { v = v2; who = w2; }
            }
            int wt = __shfl(bt[0], who);
            if (col == s) {
                part_d[obase + s] = v;
                part_i[obase + s] = n0 + wt * 16 + (who & 15);
            }
            if (lane == who) {
#pragma unroll
                for (int j = 0; j < KNBR - 1; ++j) { bd[j] = bd[j + 1]; bt[j] = bt[j + 1]; }
                bd[KNBR - 1] = FLT_MAX;
            }
        }
    }
}

// ---------------------------------------------------------------- kernel 4
// Merge 64 sorted 8-lists per (q,h) -> global top-8, dist = sqrt(qn2+key).
// grid = NQ*H, block = 64 (lane = chunk)
__global__ __launch_bounds__(64) void knn_merge(const float* __restrict__ part_d,
                                                const int* __restrict__ part_i,
                                                const float* __restrict__ pn2h,
                                                const int* __restrict__ edges,
                                                float* __restrict__ knn_d,
                                                int* __restrict__ knn_i) {
    const int lane = threadIdx.x;
    const int qh = blockIdx.x;              // q*H + h
    const int q = qh / H, h = qh % H;
    const float qn2 = pn2h[(size_t)h * NN + edges[q]];
    float d[KNBR]; int idx[KNBR];
    size_t base = ((size_t)qh * NC + lane) * KNBR;
#pragma unroll
    for (int j = 0; j < KNBR; ++j) { d[j] = part_d[base + j]; idx[j] = part_i[base + j]; }
    for (int s = 0; s < KNBR; ++s) {
        float v = d[0]; int who = lane;
#pragma unroll
        for (int off = 1; off < 64; off <<= 1) {
            float v2 = __shfl_xor(v, off);
            int   w2 = __shfl_xor(who, off);
            if (v2 < v || (v2 == v && w2 < who)) { v = v2; who = w2; }
        }
        int wi = __shfl(idx[0], who);
        if (lane == 0) {
            knn_d[(size_t)qh * KNBR + s] = sqrtf(fmaxf(qn2 + v, 0.f));
            knn_i[(size_t)qh * KNBR + s] = wi;
        }
        if (lane == who) {
#pragma unroll
            for (int j = 0; j < KNBR - 1; ++j) { d[j] = d[j + 1]; idx[j] = idx[j + 1]; }
            d[KNBR - 1] = FLT_MAX;
        }
    }
}

// ---------------------------------------------------------------- kernel 5
// Per-edge logits + softmax(+8 sentinels dist=1, logit=0) + sigmoid(mean_h).
// grid = B, block = 64: lane = h*16 + t, t<8: src side, t>=8: dst side
__global__ __launch_bounds__(64) void finalize(const float* __restrict__ pos,
                                               const float* __restrict__ grads,
                                               const float* __restrict__ adj,
                                               const float* __restrict__ label_w,
                                               const int* __restrict__ edges,
                                               const float* __restrict__ knn_d,
                                               const int* __restrict__ knn_i,
                                               float* __restrict__ out) {
    const int b = blockIdx.x;
    const int lane = threadIdx.x;
    const int h = lane >> 4;
    const int t = lane & 15;
    const int sb = edges[b];
    const int db = edges[B + b];
    const float lw = label_w[0];

    int q, qn, gn;
    if (t < KNBR) { q = b;     qn = sb; gn = db; }   // src side: grads at dst
    else          { q = B + b; qn = db; gn = sb; }   // dst side: grads at src
    const int k = t & 7;
    const size_t kk = ((size_t)q * H + h) * KNBR + k;
    const int j = knn_i[kk];
    const float dist = knn_d[kk];
    const size_t adj_idx = (t < KNBR) ? ((size_t)j * NN + db) : ((size_t)sb * NN + j);

    const float* pq = pos + ((size_t)qn * H + h) * D;
    const float* pj = pos + ((size_t)j * H + h) * D;
    const float* g = grads + ((size_t)gn * H + h) * D;
    float contrib = 0.f;
#pragma unroll
    for (int d = 0; d < D; ++d) contrib = fmaf(pq[d] - pj[d], g[d], contrib);
    float logit = fmaf(lw, adj[adj_idx], contrib);

    // softmax over 24 entries (16 real + 8 sentinels at dist 1.0, logit 0)
    float dmin = dist;
#pragma unroll
    for (int off = 1; off < 16; off <<= 1) dmin = fminf(dmin, __shfl_xor(dmin, off));
    dmin = fminf(dmin, 1.0f);
    float e = expf(dmin - dist);
    float num = e * logit;
    float den = e;
#pragma unroll
    for (int off = 1; off < 16; off <<= 1) {
        num += __shfl_xor(num, off);
        den += __shfl_xor(den, off);
    }
    den += 8.f * expf(dmin - 1.0f);
    float val = num / den;

#pragma unroll
    for (int off = 1; off < 64; off <<= 1) val += __shfl_xor(val, off);
    if (lane == 0) {
        float m = val * (1.f / 64.f);
        out[b] = 1.f / (1.f + expf(-m));
    }
}

// ----------------------------------------------------------------
extern "C" void kernel_launch(void* const* d_in, const int* in_sizes, int n_in,
                              void* d_out, int out_size, void* d_ws, size_t ws_size,
                              hipStream_t stream) {
    const float* pos     = (const float*)d_in[0];
    const float* grads   = (const float*)d_in[1];
    const float* adj     = (const float*)d_in[2];
    const float* label_w = (const float*)d_in[3];
    const int*   edges   = (const int*)d_in[4];
    float* out = (float*)d_out;

    // workspace layout (~26 MB)
    ushort* posb  = (ushort*)d_ws;                                   // H*N*D bf16
    float*  pn2h  = (float*)(posb + (size_t)H * NN * D);             // H*N
    ushort* qb    = (ushort*)(pn2h + (size_t)H * NN);                // H*NQ*D
    float*  part_d = (float*)(qb + (size_t)H * NQ * D);              // NQ*H*NC*8
    int*    part_i = (int*)(part_d + (size_t)NQ * H * NC * KNBR);
    float*  knn_dd = (float*)(part_i + (size_t)NQ * H * NC * KNBR);  // NQ*H*8
    int*    knn_ii = (int*)(knn_dd + (size_t)NQ * H * KNBR);

    prep_pos<<<(NN * H + 255) / 256, 256, 0, stream>>>(pos, posb, pn2h);
    prep_q<<<(H * NQ * D + 255) / 256, 256, 0, stream>>>(posb, edges, qb);
    knn_mfma<<<dim3(NQ / 16, H, NC), 64, 0, stream>>>(posb, pn2h, qb, edges, part_d, part_i);
    knn_merge<<<NQ * H, 64, 0, stream>>>(part_d, part_i, pn2h, edges, knn_dd, knn_ii);
    finalize<<<B, 64, 0, stream>>>(pos, grads, adj, label_w, edges, knn_dd, knn_ii, out);
}

// Round 3
// 1330.570 us; speedup vs baseline: 1.3892x; 1.0946x over previous
//
#include <hip/hip_runtime.h>
#include <hip/hip_bf16.h>
#include <cfloat>
#include <cmath>

// Problem constants
#define NN 16384
#define H 4
#define D 64
#define B 512
#define KNBR 8            // neighbors kept per side
#define NC 16             // node chunks
#define CHUNK (NN / NC)   // 1024 nodes per chunk
#define NQ (2 * B)        // 1024 queries (src then dst)

typedef __attribute__((ext_vector_type(8))) short bf16x8;   // 8 bf16 = 4 VGPRs
typedef __attribute__((ext_vector_type(4))) float f32x4;
typedef unsigned long long ull;

static __device__ __forceinline__ ushort f2bf(float v) {
    __hip_bfloat16 b = __float2bfloat16(v);
    return *(ushort*)&b;
}

// ---------------------------------------------------------------- kernel 1
// pn2h[h*N+n] = |pos[n,h,:]|^2 (exact fp32); posb[h][n][d] = bf16(pos[n,h,d])
__global__ __launch_bounds__(256) void prep_pos(const float* __restrict__ pos,
                                                ushort* __restrict__ posb,
                                                float* __restrict__ pn2h) {
    int i = blockIdx.x * 256 + threadIdx.x;       // i = h*NN + n
    if (i >= NN * H) return;
    int h = i / NN, n = i % NN;
    const float* src = pos + ((size_t)n * H + h) * D;
    ushort* dst = posb + (size_t)i * D;
    float s = 0.f;
#pragma unroll
    for (int d = 0; d < D; d += 4) {
        float4 v = *(const float4*)(src + d);
        s += v.x * v.x + v.y * v.y + v.z * v.z + v.w * v.w;
        ushort4 u; u.x = f2bf(v.x); u.y = f2bf(v.y); u.z = f2bf(v.z); u.w = f2bf(v.w);
        *(ushort4*)(dst + d) = u;
    }
    pn2h[i] = s;
}

// ---------------------------------------------------------------- kernel 2
// qb[h][q][d] = posb[h][edges[q]][d]
__global__ __launch_bounds__(256) void prep_q(const ushort* __restrict__ posb,
                                              const int* __restrict__ edges,
                                              ushort* __restrict__ qb) {
    int tid = blockIdx.x * 256 + threadIdx.x;     // h*NQ*64 + q*64 + d
    if (tid >= H * NQ * D) return;
    int d = tid & 63;
    int q = (tid >> 6) & (NQ - 1);
    int h = tid >> 16;                            // /(NQ*64)
    int node = edges[q];
    qb[tid] = posb[((size_t)h * NN + node) * D + d];
}

// ---------------------------------------------------------------- kernel 3
// MFMA distance tiles + fused per-chunk top-8 (packed u64 = d2bits<<32 | node).
// grid = (NQ/16, H, NC), block = 64 (one wave).
// Per block: 16 queries x 1024 nodes, 64 col-tiles in 16 groups of 4.
// acc kept to 4 tiles at a time to cap VGPRs; running per-lane sorted top-8
// per query row; one 16-lane pop-merge per row at the end.
__global__ __launch_bounds__(64, 3) void knn_mfma(const ushort* __restrict__ posb,
                                                  const float* __restrict__ pn2h,
                                                  const ushort* __restrict__ qb,
                                                  const int* __restrict__ edges,
                                                  ull* __restrict__ part) {
    const int lane = threadIdx.x;
    const int qt = blockIdx.x;        // query tile (16 queries)
    const int h  = blockIdx.y;
    const int c  = blockIdx.z;        // node chunk (1024 nodes)
    const int col  = lane & 15;
    const int quad = lane >> 4;
    const int n0 = c * CHUNK;

    // A fragments: row q = qt*16+col, k = quad*8 + {0..7} (+32 for a1)
    const ushort* qrow = qb + ((size_t)h * NQ + qt * 16 + col) * D + quad * 8;
    const bf16x8 a0 = *(const bf16x8*)qrow;
    const bf16x8 a1 = *(const bf16x8*)(qrow + 32);

    // query node ids + |q|^2 for my 4 rows (rows m = quad*4 + r)
    int qn[4]; float qn2[4];
#pragma unroll
    for (int r = 0; r < 4; ++r) {
        qn[r] = edges[qt * 16 + quad * 4 + r];
        qn2[r] = pn2h[(size_t)h * NN + qn[r]];
    }

    ull lst[4][KNBR];
#pragma unroll
    for (int r = 0; r < 4; ++r)
#pragma unroll
        for (int j = 0; j < KNBR; ++j) lst[r][j] = ~0ull;

    const ushort* prow = posb + ((size_t)h * NN + n0 + col) * D + quad * 8;
    const float* p2base = pn2h + (size_t)h * NN + n0 + col;

    for (int g = 0; g < 16; ++g) {
        bf16x8 b0[4], b1[4];
#pragma unroll
        for (int u = 0; u < 4; ++u) {
            const ushort* pr = prow + (size_t)(g * 4 + u) * 16 * D;
            b0[u] = *(const bf16x8*)pr;
            b1[u] = *(const bf16x8*)(pr + 32);
        }
        f32x4 acc[4];
#pragma unroll
        for (int u = 0; u < 4; ++u) {
            f32x4 z = {0.f, 0.f, 0.f, 0.f};
            z = __builtin_amdgcn_mfma_f32_16x16x32_bf16(a0, b0[u], z, 0, 0, 0);
            acc[u] = __builtin_amdgcn_mfma_f32_16x16x32_bf16(a1, b1[u], z, 0, 0, 0);
        }
        float p2[4];
#pragma unroll
        for (int u = 0; u < 4; ++u) p2[u] = p2base[(g * 4 + u) * 16];

#pragma unroll
        for (int u = 0; u < 4; ++u) {
            const int node = n0 + (g * 4 + u) * 16 + col;
#pragma unroll
            for (int r = 0; r < 4; ++r) {
                float d2 = fmaxf(fmaf(-2.f, acc[u][r], p2[u] + qn2[r]), 0.f);
                ull cand = (((ull)__float_as_uint(d2)) << 32) | (unsigned)node;
                if (node == qn[r]) cand = ~0ull;          // exclude self
                if (cand < lst[r][KNBR - 1]) {
                    ull cc = cand;
#pragma unroll
                    for (int j = 0; j < KNBR; ++j) {
                        if (cc < lst[r][j]) { ull t = lst[r][j]; lst[r][j] = cc; cc = t; }
                    }
                }
            }
        }
    }

    // 16-lane pop-merge per query row (4 rows in parallel across quads).
    // Candidates are unique (node id in low bits) -> equality identifies winner.
#pragma unroll
    for (int r = 0; r < 4; ++r) {
        const int pq = qt * 16 + quad * 4 + r;
        const size_t obase = (((size_t)pq * H + h) * NC + c) * KNBR;
        for (int s = 0; s < KNBR; ++s) {
            ull v = lst[r][0];
#pragma unroll
            for (int off = 1; off < 16; off <<= 1) {
                ull v2 = __shfl_xor(v, off);
                v = v2 < v ? v2 : v;
            }
            if (col == s) part[obase + s] = v;
            if (lst[r][0] == v) {
#pragma unroll
                for (int j = 0; j < KNBR - 1; ++j) lst[r][j] = lst[r][j + 1];
                lst[r][KNBR - 1] = ~0ull;
            }
        }
    }
}

// ---------------------------------------------------------------- kernel 4
// Merge 16 chunks x 8 = 128 packed candidates per (q,h) -> global top-8.
// grid = NQ*H, block = 64; lane holds 2 candidates as a sorted pair.
__global__ __launch_bounds__(64) void knn_merge(const ull* __restrict__ part,
                                                float* __restrict__ knn_d,
                                                int* __restrict__ knn_i) {
    const int lane = threadIdx.x;
    const int qh = blockIdx.x;              // q*H + h
    const size_t base = (size_t)qh * (NC * KNBR);
    ull v0 = part[base + lane];
    ull v1 = part[base + 64 + lane];
    ull lo = v0 < v1 ? v0 : v1;
    ull hi = v0 < v1 ? v1 : v0;
    for (int s = 0; s < KNBR; ++s) {
        ull m = lo;
#pragma unroll
        for (int off = 1; off < 64; off <<= 1) {
            ull m2 = __shfl_xor(m, off);
            m = m2 < m ? m2 : m;
        }
        if (lane == 0) {
            float d2 = __uint_as_float((unsigned)(m >> 32));
            knn_d[(size_t)qh * KNBR + s] = sqrtf(d2);
            knn_i[(size_t)qh * KNBR + s] = (int)(unsigned)(m & 0xFFFFFFFFu);
        }
        if (lo == m) { lo = hi; hi = ~0ull; }
    }
}

// ---------------------------------------------------------------- kernel 5
// Per-edge logits + softmax(+8 sentinels dist=1, logit=0) + sigmoid(mean_h).
// grid = B, block = 64: lane = h*16 + t, t<8: src side, t>=8: dst side
__global__ __launch_bounds__(64) void finalize(const float* __restrict__ pos,
                                               const float* __restrict__ grads,
                                               const float* __restrict__ adj,
                                               const float* __restrict__ label_w,
                                               const int* __restrict__ edges,
                                               const float* __restrict__ knn_d,
                                               const int* __restrict__ knn_i,
                                               float* __restrict__ out) {
    const int b = blockIdx.x;
    const int lane = threadIdx.x;
    const int h = lane >> 4;
    const int t = lane & 15;
    const int sb = edges[b];
    const int db = edges[B + b];
    const float lw = label_w[0];

    int q, qn, gn;
    if (t < KNBR) { q = b;     qn = sb; gn = db; }   // src side: grads at dst
    else          { q = B + b; qn = db; gn = sb; }   // dst side: grads at src
    const int k = t & 7;
    const size_t kk = ((size_t)q * H + h) * KNBR + k;
    const int j = knn_i[kk];
    const float dist = knn_d[kk];
    const size_t adj_idx = (t < KNBR) ? ((size_t)j * NN + db) : ((size_t)sb * NN + j);

    const float4* pq4 = (const float4*)(pos + ((size_t)qn * H + h) * D);
    const float4* pj4 = (const float4*)(pos + ((size_t)j * H + h) * D);
    const float4* g4  = (const float4*)(grads + ((size_t)gn * H + h) * D);
    float contrib = 0.f;
#pragma unroll
    for (int d = 0; d < D / 4; ++d) {
        float4 a = pq4[d], p = pj4[d], g = g4[d];
        contrib = fmaf(a.x - p.x, g.x, contrib);
        contrib = fmaf(a.y - p.y, g.y, contrib);
        contrib = fmaf(a.z - p.z, g.z, contrib);
        contrib = fmaf(a.w - p.w, g.w, contrib);
    }
    float logit = fmaf(lw, adj[adj_idx], contrib);

    // softmax over 24 entries (16 real + 8 sentinels at dist 1.0, logit 0)
    float dmin = dist;
#pragma unroll
    for (int off = 1; off < 16; off <<= 1) dmin = fminf(dmin, __shfl_xor(dmin, off));
    dmin = fminf(dmin, 1.0f);
    float e = expf(dmin - dist);
    float num = e * logit;
    float den = e;
#pragma unroll
    for (int off = 1; off < 16; off <<= 1) {
        num += __shfl_xor(num, off);
        den += __shfl_xor(den, off);
    }
    den += 8.f * expf(dmin - 1.0f);
    float val = num / den;

#pragma unroll
    for (int off = 1; off < 64; off <<= 1) val += __shfl_xor(val, off);
    if (lane == 0) {
        float m = val * (1.f / 64.f);
        out[b] = 1.f / (1.f + expf(-m));
    }
}

// ----------------------------------------------------------------
extern "C" void kernel_launch(void* const* d_in, const int* in_sizes, int n_in,
                              void* d_out, int out_size, void* d_ws, size_t ws_size,
                              hipStream_t stream) {
    const float* pos     = (const float*)d_in[0];
    const float* grads   = (const float*)d_in[1];
    const float* adj     = (const float*)d_in[2];
    const float* label_w = (const float*)d_in[3];
    const int*   edges   = (const int*)d_in[4];
    float* out = (float*)d_out;

    // workspace layout (~13 MB; u64 array first for 8B alignment)
    ull*    part  = (ull*)d_ws;                                      // NQ*H*NC*8
    ushort* posb  = (ushort*)(part + (size_t)NQ * H * NC * KNBR);    // H*N*D bf16
    float*  pn2h  = (float*)(posb + (size_t)H * NN * D);             // H*N
    ushort* qb    = (ushort*)(pn2h + (size_t)H * NN);                // H*NQ*D
    float*  knn_dd = (float*)(qb + (size_t)H * NQ * D);              // NQ*H*8
    int*    knn_ii = (int*)(knn_dd + (size_t)NQ * H * KNBR);

    prep_pos<<<(NN * H + 255) / 256, 256, 0, stream>>>(pos, posb, pn2h);
    prep_q<<<(H * NQ * D + 255) / 256, 256, 0, stream>>>(posb, edges, qb);
    knn_mfma<<<dim3(NQ / 16, H, NC), 64, 0, stream>>>(posb, pn2h, qb, edges, part);
    knn_merge<<<NQ * H, 64, 0, stream>>>(part, knn_dd, knn_ii);
    finalize<<<B, 64, 0, stream>>>(pos, grads, adj, label_w, edges, knn_dd, knn_ii, out);
}